// Round 1
// baseline (191.130 us; speedup 1.0000x reference)
//
#include <hip/hip_runtime.h>

typedef __bf16 bf16x4 __attribute__((ext_vector_type(4)));
typedef __bf16 bf16x8 __attribute__((ext_vector_type(8)));
typedef float f32x16 __attribute__((ext_vector_type(16)));

// ---- workspace layout (bf16 element offsets), FRAGMENT-ORDERED weights ----
// A wave's weight frag for (n-tile, k-block) is 64 lanes x 16 B = 1 KB contig:
//   elem (lane, j) at ((nt*NKBLK + kk)*64 + lane)*8 + j
//   encodes n = nt*32 + (lane&31), k = kk*16 + (lane>>5)*8 + j
#define W0F_OFF 0                 // 16 nt x 1 kk  x 64 x 8  = 8192
#define W1F_OFF 8192              // 16 nt x 32 kk x 64 x 8  = 262144
#define W2F_OFF (8192 + 262144)   // 5 nt  x 32 kk x 64 x 8  = 81920 (n>=136 zero)
#define PREP_TOTAL (8192 + 262144 + 81920)

__global__ void prep_weights(const float* __restrict__ W0,
                             const float* __restrict__ W1,
                             const float* __restrict__ W2,
                             __bf16* __restrict__ ws) {
    int t = blockIdx.x * 256 + threadIdx.x;
    if (t < 8192) {
        int j = t & 7, lane = (t >> 3) & 63, nt = t >> 9;
        int n = nt * 32 + (lane & 31);
        int k = (lane >> 5) * 8 + j;              // < 16
        ws[W0F_OFF + t] = (__bf16)W0[k * 512 + n];
    } else if (t < 8192 + 262144) {
        int u = t - 8192;
        int j = u & 7, lane = (u >> 3) & 63;
        int x = u >> 9;                            // nt*32 + kk
        int kk = x & 31, nt = x >> 5;
        int n = nt * 32 + (lane & 31);
        int k = kk * 16 + (lane >> 5) * 8 + j;
        ws[W1F_OFF + u] = (__bf16)W1[k * 512 + n];
    } else if (t < PREP_TOTAL) {
        int v = t - (8192 + 262144);
        int j = v & 7, lane = (v >> 3) & 63;
        int x = v >> 9;                            // nt*32 + kk
        int kk = x & 31, nt = x >> 5;
        int n = nt * 32 + (lane & 31);
        int k = kk * 16 + (lane >> 5) * 8 + j;
        ws[W2F_OFF + v] = (n < 136) ? (__bf16)W2[k * 136 + n] : (__bf16)0.0f;
    }
}

__device__ __forceinline__ float fast_tanh(float x) {
#if __has_builtin(__builtin_amdgcn_exp2f)
    float e = __builtin_amdgcn_exp2f(x * 2.885390081777926f);
#else
    float e = exp2f(x * 2.885390081777926f);
#endif
    return 1.0f - 2.0f * __builtin_amdgcn_rcpf(e + 1.0f);
}

// h LDS: [128][520] bf16 (rows 1040 B, 16B-aligned), ds_read_b128 conflict-free
// (16-lane phases, 2-way max). net LDS: [128][140] f32 overlay.
#define HSTR 520
#define NSTR 140

// R18: BM=128, 8 waves x (2 nt x 4 bt), grid 1024, 1 block/CU (LDS 133 KB),
// 2 waves/SIMD. Rationale: R17's (2,2)@BM=64 needs 512 B of L2 weight traffic
// per MFMA = 64 B/cyc/CU at MFMA peak > ~56 B/cyc/CU L2 ceiling, and delivered
// only ~29% of L2 under 512-block same-line contention -> MfmaUtil plateau 30%.
// (2,4)@BM=128 halves weight bytes/MFMA to 256 B (57% of L2 ceiling) and
// halves concurrent readers per XCD, keeping LDS A-reads at 0.5/MFMA (75% of
// LDS ceiling). Occupancy drops 4->2 waves/SIMD; compensated by depth-1
// register double-buffer on the weight fragments (loads for kk-pair i+1 issued
// before the 16-MFMA cluster of pair i, >512 cyc cover). acc=128 AGPR +
// ~100 arch VGPR < 256 -> 2 waves/SIMD fits (launch_bounds enforces).
__global__ __launch_bounds__(512, 2)
void fused_mlp_quad(const float* __restrict__ points,
                    const float* __restrict__ b0,
                    const float* __restrict__ b1,
                    const float* __restrict__ b2,
                    const __bf16* __restrict__ ws,
                    float* __restrict__ out) {
    __shared__ __align__(16) unsigned char lds_raw[133120];
    __bf16* h  = (__bf16*)lds_raw;   // [128][HSTR] bf16 (h0, then h1 in place)
    float* net = (float*)lds_raw;    // [128][NSTR] f32 overlay after phase 2

    const __bf16* w0f = ws + W0F_OFF;
    const __bf16* w1f = ws + W1F_OFF;
    const __bf16* w2f = ws + W2F_OFF;

    const int tid = threadIdx.x;
    const int w   = tid >> 6;     // wave 0..7
    const int l   = tid & 63;
    const int ln  = l & 31;       // batch row within 32-tile / lane index
    const int hi  = l >> 5;       // k-half
    const int row0 = blockIdx.x * 128;

    const int lofs = l * 8;       // lane offset within a 1KB fragment record
    const int ofs16 = (blockIdx.x >> 3) & 15;   // K-rotation (16-way per XCD)

    // ---------- phase 0: h0 = tanh(x @ W0 + b0), K=16 = one MFMA step ----------
    {
        bf16x8 bx[4];
#pragma unroll
        for (int bt = 0; bt < 4; ++bt) {
            const float* src = points + (row0 + bt * 32 + ln) * 16 + hi * 8;
            float4 p0 = ((const float4*)src)[0];
            float4 p1 = ((const float4*)src)[1];
            bf16x8 v;
            v[0] = (__bf16)p0.x; v[1] = (__bf16)p0.y; v[2] = (__bf16)p0.z; v[3] = (__bf16)p0.w;
            v[4] = (__bf16)p1.x; v[5] = (__bf16)p1.y; v[6] = (__bf16)p1.z; v[7] = (__bf16)p1.w;
            bx[bt] = v;
        }
#pragma unroll
        for (int t = 0; t < 2; ++t) {
            const int ntg = w * 2 + t;
            bf16x8 wf = *(const bf16x8*)(w0f + ntg * 512 + lofs);
#pragma unroll
            for (int bt = 0; bt < 4; ++bt) {
                f32x16 acc = {};
                acc = __builtin_amdgcn_mfma_f32_32x32x16_bf16(wf, bx[bt], acc, 0, 0, 0);
#pragma unroll
                for (int rg = 0; rg < 4; ++rg) {
                    const int n0 = ntg * 32 + 8 * rg + 4 * hi;
                    float4 bias = *(const float4*)(b0 + n0);
                    bf16x4 v;
                    v[0] = (__bf16)fast_tanh(acc[4 * rg + 0] + bias.x);
                    v[1] = (__bf16)fast_tanh(acc[4 * rg + 1] + bias.y);
                    v[2] = (__bf16)fast_tanh(acc[4 * rg + 2] + bias.z);
                    v[3] = (__bf16)fast_tanh(acc[4 * rg + 3] + bias.w);
                    *(bf16x4*)(h + (bt * 32 + ln) * HSTR + n0) = v;
                }
            }
        }
    }
    __syncthreads();

    // ---------- phase 1: h1 = tanh(h0 @ W1 + b1) ----------
    // wave: 2 nt x 4 bt; acc = 128 AGPR. Depth-1 weight prefetch, rotated start.
    f32x16 acc1[4][2] = {};   // [bt][t]
    {
        const __bf16* ab = h + ln * HSTR + hi * 8;
        const __bf16* wb0 = w1f + (w * 2 + 0) * 16384 + lofs;
        const __bf16* wb1 = w1f + (w * 2 + 1) * 16384 + lofs;
        bf16x8 nb00, nb01, nb10, nb11;            // next-iter weights [u][t]
        {
            const int kk0 = ofs16 * 2;
            nb00 = *(const bf16x8*)(wb0 + kk0 * 512);
            nb01 = *(const bf16x8*)(wb1 + kk0 * 512);
            nb10 = *(const bf16x8*)(wb0 + (kk0 + 1) * 512);
            nb11 = *(const bf16x8*)(wb1 + (kk0 + 1) * 512);
        }
        for (int ks2 = 0; ks2 < 16; ++ks2) {
            const int ks  = (ks2 + ofs16) & 15;
            const int ksn = (ks2 + 1 + ofs16) & 15;
            const bf16x8 bb00 = nb00, bb01 = nb01, bb10 = nb10, bb11 = nb11;
            bf16x8 aa[2][4];
#pragma unroll
            for (int u = 0; u < 2; ++u) {
                const int ko = (ks * 2 + u) * 16;
#pragma unroll
                for (int bt = 0; bt < 4; ++bt)
                    aa[u][bt] = *(const bf16x8*)(ab + bt * 32 * HSTR + ko);
            }
            {   // prefetch next kk-pair's weights (last iter harmlessly rewraps)
                const int kk0 = ksn * 2;
                nb00 = *(const bf16x8*)(wb0 + kk0 * 512);
                nb01 = *(const bf16x8*)(wb1 + kk0 * 512);
                nb10 = *(const bf16x8*)(wb0 + (kk0 + 1) * 512);
                nb11 = *(const bf16x8*)(wb1 + (kk0 + 1) * 512);
            }
#pragma unroll
            for (int bt = 0; bt < 4; ++bt) {
                acc1[bt][0] = __builtin_amdgcn_mfma_f32_32x32x16_bf16(bb00, aa[0][bt], acc1[bt][0], 0, 0, 0);
                acc1[bt][1] = __builtin_amdgcn_mfma_f32_32x32x16_bf16(bb01, aa[0][bt], acc1[bt][1], 0, 0, 0);
            }
#pragma unroll
            for (int bt = 0; bt < 4; ++bt) {
                acc1[bt][0] = __builtin_amdgcn_mfma_f32_32x32x16_bf16(bb10, aa[1][bt], acc1[bt][0], 0, 0, 0);
                acc1[bt][1] = __builtin_amdgcn_mfma_f32_32x32x16_bf16(bb11, aa[1][bt], acc1[bt][1], 0, 0, 0);
            }
        }
    }
    __syncthreads();   // all h0 reads done; overwrite in place
#pragma unroll
    for (int t = 0; t < 2; ++t) {
#pragma unroll
        for (int bt = 0; bt < 4; ++bt) {
#pragma unroll
            for (int rg = 0; rg < 4; ++rg) {
                const int n0 = (w * 2 + t) * 32 + 8 * rg + 4 * hi;
                float4 bias = *(const float4*)(b1 + n0);
                bf16x4 v;
                v[0] = (__bf16)fast_tanh(acc1[bt][t][4 * rg + 0] + bias.x);
                v[1] = (__bf16)fast_tanh(acc1[bt][t][4 * rg + 1] + bias.y);
                v[2] = (__bf16)fast_tanh(acc1[bt][t][4 * rg + 2] + bias.z);
                v[3] = (__bf16)fast_tanh(acc1[bt][t][4 * rg + 3] + bias.w);
                *(bf16x4*)(h + (bt * 32 + ln) * HSTR + n0) = v;
            }
        }
    }
    __syncthreads();

    // ---------- phase 2: net = h1 @ W2 + b2 (N pad 160: 5 nt x 4 bt = 20 tiles) ----
    // waves 0-3: nts {0,1,2}, bt = w. waves 4-7: nts {3,4}, bt = w-4.
    // Balanced MFMA issue per SIMD (96 vs 64 per wave -> 160/SIMD).
    f32x16 acc2[3] = {};
    const bool three = (w < 4);
    const int my_bt = three ? w : (w - 4);
    const int ntb   = three ? 0 : 3;
    {
        const __bf16* arow2 = h + (my_bt * 32 + ln) * HSTR + hi * 8;
        const __bf16* wq0 = w2f + (ntb + 0) * 16384 + lofs;
        const __bf16* wq1 = w2f + (ntb + 1) * 16384 + lofs;
        const __bf16* wq2 = w2f + 2 * 16384 + lofs;   // nt=2, only when three
        bf16x8 nw00, nw01, nw10, nw11;
        bf16x8 nw02 = {}, nw12 = {};
        {
            const int kk0 = ofs16 * 2;
            nw00 = *(const bf16x8*)(wq0 + kk0 * 512);
            nw01 = *(const bf16x8*)(wq1 + kk0 * 512);
            nw10 = *(const bf16x8*)(wq0 + (kk0 + 1) * 512);
            nw11 = *(const bf16x8*)(wq1 + (kk0 + 1) * 512);
            if (three) {
                nw02 = *(const bf16x8*)(wq2 + kk0 * 512);
                nw12 = *(const bf16x8*)(wq2 + (kk0 + 1) * 512);
            }
        }
        for (int ks2 = 0; ks2 < 16; ++ks2) {
            const int ks  = (ks2 + ofs16) & 15;
            const int ksn = (ks2 + 1 + ofs16) & 15;
            const bf16x8 b00 = nw00, b01 = nw01, b02 = nw02;
            const bf16x8 b10 = nw10, b11 = nw11, b12 = nw12;
            bf16x8 aa0 = *(const bf16x8*)(arow2 + (ks * 2 + 0) * 16);
            bf16x8 aa1 = *(const bf16x8*)(arow2 + (ks * 2 + 1) * 16);
            {
                const int kk0 = ksn * 2;
                nw00 = *(const bf16x8*)(wq0 + kk0 * 512);
                nw01 = *(const bf16x8*)(wq1 + kk0 * 512);
                nw10 = *(const bf16x8*)(wq0 + (kk0 + 1) * 512);
                nw11 = *(const bf16x8*)(wq1 + (kk0 + 1) * 512);
                if (three) {
                    nw02 = *(const bf16x8*)(wq2 + kk0 * 512);
                    nw12 = *(const bf16x8*)(wq2 + (kk0 + 1) * 512);
                }
            }
            acc2[0] = __builtin_amdgcn_mfma_f32_32x32x16_bf16(b00, aa0, acc2[0], 0, 0, 0);
            acc2[1] = __builtin_amdgcn_mfma_f32_32x32x16_bf16(b01, aa0, acc2[1], 0, 0, 0);
            if (three)
                acc2[2] = __builtin_amdgcn_mfma_f32_32x32x16_bf16(b02, aa0, acc2[2], 0, 0, 0);
            acc2[0] = __builtin_amdgcn_mfma_f32_32x32x16_bf16(b10, aa1, acc2[0], 0, 0, 0);
            acc2[1] = __builtin_amdgcn_mfma_f32_32x32x16_bf16(b11, aa1, acc2[1], 0, 0, 0);
            if (three)
                acc2[2] = __builtin_amdgcn_mfma_f32_32x32x16_bf16(b12, aa1, acc2[2], 0, 0, 0);
        }
    }
    __syncthreads();   // all h1 reads done; overwrite with net (fp32)
    {
        const int r = my_bt * 32 + ln;
        if (three) {
#pragma unroll
            for (int q = 0; q < 3; ++q) {
#pragma unroll
                for (int rg = 0; rg < 4; ++rg) {
                    const int n0 = q * 32 + 8 * rg + 4 * hi;   // <= 92
                    float4 bias = *(const float4*)(b2 + n0);
                    float4 v;
                    v.x = acc2[q][4 * rg + 0] + bias.x;
                    v.y = acc2[q][4 * rg + 1] + bias.y;
                    v.z = acc2[q][4 * rg + 2] + bias.z;
                    v.w = acc2[q][4 * rg + 3] + bias.w;
                    *(float4*)(net + r * NSTR + n0) = v;
                }
            }
        } else {
#pragma unroll
            for (int rg = 0; rg < 4; ++rg) {
                const int n0 = 96 + 8 * rg + 4 * hi;           // <= 124
                float4 bias = *(const float4*)(b2 + n0);
                float4 v;
                v.x = acc2[0][4 * rg + 0] + bias.x;
                v.y = acc2[0][4 * rg + 1] + bias.y;
                v.z = acc2[0][4 * rg + 2] + bias.z;
                v.w = acc2[0][4 * rg + 3] + bias.w;
                *(float4*)(net + r * NSTR + n0) = v;
            }
            {   // nt=4 (n 128..135): only rg==0 in range
                const int n0 = 128 + 4 * hi;
                float4 bias = *(const float4*)(b2 + n0);
                float4 v;
                v.x = acc2[1][0] + bias.x;
                v.y = acc2[1][1] + bias.y;
                v.z = acc2[1][2] + bias.z;
                v.w = acc2[1][3] + bias.w;
                *(float4*)(net + r * NSTR + n0) = v;
            }
        }
    }
    __syncthreads();

    // ---------- phase 3: vals = ||M^T x||^2 + eps*||x||^2 ----------
    // 8 threads per row x 64 rows per pass, 2 passes for 128 rows
    {
        const int r8 = tid >> 3;
        const int jg = tid & 7;
#pragma unroll
        for (int half = 0; half < 2; ++half) {
            const int r = r8 + half * 64;
            const float* xp = points + (row0 + r) * 16;
            float xv[16];
#pragma unroll
            for (int i = 0; i < 4; ++i) {
                float4 v = ((const float4*)xp)[i];
                xv[i * 4 + 0] = v.x; xv[i * 4 + 1] = v.y;
                xv[i * 4 + 2] = v.z; xv[i * 4 + 3] = v.w;
            }
            float sumsq = 0.f;
#pragma unroll
            for (int i = 0; i < 16; ++i) sumsq += xv[i] * xv[i];
            float p = 0.f;
#pragma unroll
            for (int jj = 0; jj < 2; ++jj) {
                const int j = jg + jj * 8;
                float y = 0.f;
#pragma unroll
                for (int i = 0; i < 16; ++i) {
                    float mv = net[r * NSTR + ((i * (i + 1)) >> 1) + j];
                    y += (i >= j) ? mv * xv[i] : 0.f;
                }
                p += y * y;
            }
            p += __shfl_xor(p, 1);
            p += __shfl_xor(p, 2);
            p += __shfl_xor(p, 4);
            if (jg == 0) out[row0 + r] = p + 1e-6f * sumsq;
        }
    }
}

extern "C" void kernel_launch(void* const* d_in, const int* in_sizes, int n_in,
                              void* d_out, int out_size, void* d_ws, size_t ws_size,
                              hipStream_t stream) {
    const float* points = (const float*)d_in[0];
    const float* W0 = (const float*)d_in[1];
    const float* b0 = (const float*)d_in[2];
    const float* W1 = (const float*)d_in[3];
    const float* b1 = (const float*)d_in[4];
    const float* W2 = (const float*)d_in[5];
    const float* b2 = (const float*)d_in[6];
    __bf16* ws = (__bf16*)d_ws;
    float* out = (float*)d_out;

    prep_weights<<<(PREP_TOTAL + 255) / 256, 256, 0, stream>>>(W0, W1, W2, ws);

    const int B = in_sizes[0] / 16;   // 131072
    fused_mlp_quad<<<B / 128, 512, 0, stream>>>(points, b0, b1, b2, ws, out);
}